// Round 5
// baseline (369.783 us; speedup 1.0000x reference)
//
#include <hip/hip_runtime.h>
#include <hip/hip_bf16.h>

#define BATCH 8
#define SEQ   2048
#define DIM   128
#define NROWS 16384              // BATCH*SEQ
#define INV_2SQRTD 0.04419417382415922f   // 1/(2*sqrt(128))

typedef __bf16 bf16x8  __attribute__((ext_vector_type(8)));
typedef float  floatx16 __attribute__((ext_vector_type(16)));

static __device__ __forceinline__ unsigned short f2bf(float v) {
    union { __hip_bfloat16 h; unsigned short u; } c;
    c.h = __float2bfloat16(v);
    return c.u;
}
static __device__ __forceinline__ float bf2f(unsigned short u) {
    union { unsigned int i; float f; } c;
    c.i = (unsigned int)u << 16;
    return c.f;
}

// ---------------------------------------------------------------------------
// Transpose both weight matrices W[d][e] -> Wt[e][d] (f32 128x128).
// grid (2,2,2): z selects Wq/Wk. 64x64 tiles, LDS-padded.
// ---------------------------------------------------------------------------
__global__ void __launch_bounds__(256)
transpose_w2(const float* __restrict__ Wq, const float* __restrict__ Wk,
             float* __restrict__ Wqt, float* __restrict__ Wkt) {
    const float* src = blockIdx.z ? Wk : Wq;
    float*       dst = blockIdx.z ? Wkt : Wqt;
    __shared__ float tile[64][65];
    const int c0 = blockIdx.x * 64;
    const int r0 = blockIdx.y * 64;
    const int tx = threadIdx.x & 15, ty = threadIdx.x >> 4;
#pragma unroll
    for (int k = 0; k < 4; ++k) {
        float4 v = *reinterpret_cast<const float4*>(
            src + (size_t)(r0 + ty + 16*k)*DIM + c0 + tx*4);
        tile[ty + 16*k][tx*4+0] = v.x;
        tile[ty + 16*k][tx*4+1] = v.y;
        tile[ty + 16*k][tx*4+2] = v.z;
        tile[ty + 16*k][tx*4+3] = v.w;
    }
    __syncthreads();
#pragma unroll
    for (int k = 0; k < 4; ++k) {
        float4 o;
        o.x = tile[tx*4+0][ty+16*k];
        o.y = tile[tx*4+1][ty+16*k];
        o.z = tile[tx*4+2][ty+16*k];
        o.w = tile[tx*4+3][ty+16*k];
        *reinterpret_cast<float4*>(
            dst + (size_t)(c0 + ty + 16*k)*DIM + r0 + tx*4) = o;
    }
}

// ---------------------------------------------------------------------------
// Q projection: Q = X @ Wq^T + bq, written as SPLIT bf16 (hi + lo residual)
// in MFMA-A-fragment-ready layout Qblk[kt][hi][row][8]  (d = kt*16+hi*8+j).
// grid NROWS/8, block 64; lane t owns output cols {2t, 2t+1}; Wt reads are
// lane-contiguous (coalesced) — fixes round-4's 512B-strided W gathers.
// ---------------------------------------------------------------------------
__global__ void __launch_bounds__(64)
project_q(const float* __restrict__ X, const float* __restrict__ Wt,
          const float* __restrict__ bias,
          unsigned short* __restrict__ Qhi, unsigned short* __restrict__ Qlo) {
    const int row0 = blockIdx.x * 8;
    const int t = threadIdx.x;
    __shared__ float xs[8][DIM];
#pragma unroll
    for (int i = 0; i < 16; ++i) {
        const int idx = i*64 + t;
        xs[idx >> 7][idx & 127] = X[(size_t)row0*DIM + idx];
    }
    __syncthreads();
    const float2 bv = *reinterpret_cast<const float2*>(bias + 2*t);
    float2 s[8];
#pragma unroll
    for (int r = 0; r < 8; ++r) s[r] = bv;
#pragma unroll 4
    for (int e = 0; e < DIM; ++e) {
        const float2 wv = *reinterpret_cast<const float2*>(Wt + (size_t)e*DIM + 2*t);
#pragma unroll
        for (int r = 0; r < 8; ++r) {
            const float xv = xs[r][e];
            s[r].x = fmaf(xv, wv.x, s[r].x);
            s[r].y = fmaf(xv, wv.y, s[r].y);
        }
    }
    const int kt  = t >> 3;          // (2t)>>4
    const int hih = (t >> 2) & 1;    // ((2t)>>3)&1
    const int j   = (2*t) & 7;
#pragma unroll
    for (int r = 0; r < 8; ++r) {
        const size_t base = (((size_t)kt*2 + hih)*NROWS + row0 + r)*8 + j;
        const unsigned short h0 = f2bf(s[r].x);
        const unsigned short h1 = f2bf(s[r].y);
        ushort2 ph; ph.x = h0; ph.y = h1;
        ushort2 pl; pl.x = f2bf(s[r].x - bf2f(h0));
        pl.y = f2bf(s[r].y - bf2f(h1));
        *reinterpret_cast<ushort2*>(Qhi + base) = ph;
        *reinterpret_cast<ushort2*>(Qlo + base) = pl;
    }
}

// ---------------------------------------------------------------------------
// K projection: K = X @ Wk^T + bk, bf16, MFMA-B-fragment-ready layout
// Kblk[b][kt][hi][key][8].
// ---------------------------------------------------------------------------
__global__ void __launch_bounds__(64)
project_k(const float* __restrict__ X, const float* __restrict__ Wt,
          const float* __restrict__ bias, unsigned short* __restrict__ Kb) {
    const int row0 = blockIdx.x * 8;
    const int t = threadIdx.x;
    __shared__ float xs[8][DIM];
#pragma unroll
    for (int i = 0; i < 16; ++i) {
        const int idx = i*64 + t;
        xs[idx >> 7][idx & 127] = X[(size_t)row0*DIM + idx];
    }
    __syncthreads();
    const float2 bv = *reinterpret_cast<const float2*>(bias + 2*t);
    float2 s[8];
#pragma unroll
    for (int r = 0; r < 8; ++r) s[r] = bv;
#pragma unroll 4
    for (int e = 0; e < DIM; ++e) {
        const float2 wv = *reinterpret_cast<const float2*>(Wt + (size_t)e*DIM + 2*t);
#pragma unroll
        for (int r = 0; r < 8; ++r) {
            const float xv = xs[r][e];
            s[r].x = fmaf(xv, wv.x, s[r].x);
            s[r].y = fmaf(xv, wv.y, s[r].y);
        }
    }
    const int kt  = t >> 3;
    const int hih = (t >> 2) & 1;
    const int j   = (2*t) & 7;
#pragma unroll
    for (int r = 0; r < 8; ++r) {
        const int row = row0 + r;
        const int b   = row >> 11;
        const int key = row & (SEQ - 1);
        const size_t base = (size_t)b*(8*2*SEQ*8) +
                            (((size_t)kt*2 + hih)*SEQ + key)*8 + j;
        ushort2 p; p.x = f2bf(s[r].x); p.y = f2bf(s[r].y);
        *reinterpret_cast<ushort2*>(Kb + base) = p;
    }
}

// ---------------------------------------------------------------------------
// MFMA scores + exact 1.5-entmax.
// Block = 32 query rows, 4 waves; wave wv owns keys [wv*512, wv*512+512).
// v_mfma_f32_32x32x16_bf16, Q split hi/lo (2 MFMAs) for f32-level accuracy.
// C layout (m74/m101-verified): col=lane&31, row=(reg&3)+8*(reg>>2)+4*(lane>>5).
// Row max + 14-iter bisection for tau* on in-register z; cross-wave combine
// through a 512B LDS buffer.
// ---------------------------------------------------------------------------
__global__ void __launch_bounds__(256, 1)
attn_entmax_mfma(const __bf16* __restrict__ Qhi, const __bf16* __restrict__ Qlo,
                 const __bf16* __restrict__ Kb, float* __restrict__ out) {
    const int tid  = threadIdx.x;
    const int wv   = tid >> 6;
    const int lane = tid & 63;
    const int l5   = lane & 31;
    const int hi5  = lane >> 5;
    const int row0 = blockIdx.x * 32;
    const int b    = row0 >> 11;
    const int key0 = wv * 512;

    floatx16 acc[16];
    const floatx16 zerov = {};
#pragma unroll
    for (int t = 0; t < 16; ++t) acc[t] = zerov;

    const __bf16* Kbase = Kb + (size_t)b * (8*2*SEQ*8);

#pragma unroll
    for (int kt = 0; kt < 8; ++kt) {
        const size_t qoff = (((size_t)kt*2 + hi5)*NROWS + row0 + l5)*8;
        const bf16x8 ah = *reinterpret_cast<const bf16x8*>(Qhi + qoff);
        const bf16x8 al = *reinterpret_cast<const bf16x8*>(Qlo + qoff);
        const __bf16* kp = Kbase + (((size_t)kt*2 + hi5)*SEQ + key0 + l5)*8;
#pragma unroll
        for (int t = 0; t < 16; ++t) {
            const bf16x8 bk = *reinterpret_cast<const bf16x8*>(kp + (size_t)t*32*8);
            acc[t] = __builtin_amdgcn_mfma_f32_32x32x16_bf16(ah, bk, acc[t], 0, 0, 0);
            acc[t] = __builtin_amdgcn_mfma_f32_32x32x16_bf16(al, bk, acc[t], 0, 0, 0);
        }
    }

    __shared__ __align__(16) float red[32][4];

    // ---- row max over all 2048 keys ----
    float rm[16];
#pragma unroll
    for (int r = 0; r < 16; ++r) {
        float m = acc[0][r];
#pragma unroll
        for (int t = 1; t < 16; ++t) m = fmaxf(m, acc[t][r]);
#pragma unroll
        for (int off = 16; off >= 1; off >>= 1)
            m = fmaxf(m, __shfl_xor(m, off, 64));
        if (l5 == r) red[(r & 3) + 8*(r >> 2) + 4*hi5][wv] = m;
    }
    __syncthreads();
#pragma unroll
    for (int r = 0; r < 16; ++r) {
        const int row = (r & 3) + 8*(r >> 2) + 4*hi5;
        const float4 mv = *reinterpret_cast<const float4*>(red[row]);
        rm[r] = fmaxf(fmaxf(mv.x, mv.y), fmaxf(mv.z, mv.w));
    }
    __syncthreads();

    // z = (S - max) * 1/(2*sqrt(D)), in place; z <= 0, row max -> 0
#pragma unroll
    for (int r = 0; r < 16; ++r) {
        const float nm = -rm[r] * INV_2SQRTD;
#pragma unroll
        for (int t = 0; t < 16; ++t)
            acc[t][r] = fmaf(acc[t][r], INV_2SQRTD, nm);
    }

    // ---- bisection for tau*: f(tau)=sum max(z-tau,0)^2, root in [-1,0] ----
    float lo[16], hh[16];
#pragma unroll
    for (int r = 0; r < 16; ++r) { lo[r] = -1.0f; hh[r] = 0.0f; }
    for (int it = 0; it < 14; ++it) {
#pragma unroll
        for (int r = 0; r < 16; ++r) {
            const float tau = 0.5f*(lo[r] + hh[r]);
            float f = 0.0f;
#pragma unroll
            for (int t = 0; t < 16; ++t) {
                const float d = fmaxf(acc[t][r] - tau, 0.0f);
                f = fmaf(d, d, f);
            }
#pragma unroll
            for (int off = 16; off >= 1; off >>= 1)
                f += __shfl_xor(f, off, 64);
            if (l5 == r) red[(r & 3) + 8*(r >> 2) + 4*hi5][wv] = f;
        }
        __syncthreads();
#pragma unroll
        for (int r = 0; r < 16; ++r) {
            const int row = (r & 3) + 8*(r >> 2) + 4*hi5;
            const float4 fv = *reinterpret_cast<const float4*>(red[row]);
            const float fs = (fv.x + fv.y) + (fv.z + fv.w);
            const float tau = 0.5f*(lo[r] + hh[r]);
            if (fs >= 1.0f) lo[r] = tau; else hh[r] = tau;
        }
        __syncthreads();
    }

    // ---- epilogue: p = max(z - tau, 0)^2, f32 stores (coalesced 128B/half) --
#pragma unroll
    for (int r = 0; r < 16; ++r) {
        const int row = (r & 3) + 8*(r >> 2) + 4*hi5;
        const float tau = 0.5f*(lo[r] + hh[r]);
        float* op = out + (size_t)(row0 + row)*SEQ + key0 + l5;
#pragma unroll
        for (int t = 0; t < 16; ++t) {
            const float d = fmaxf(acc[t][r] - tau, 0.0f);
            op[(size_t)t*32] = d*d;
        }
    }
}

// ---------------------------------------------------------------------------
extern "C" void kernel_launch(void* const* d_in, const int* in_sizes, int n_in,
                              void* d_out, int out_size, void* d_ws, size_t ws_size,
                              hipStream_t stream) {
    const float* x_c = (const float*)d_in[0];
    const float* x_n = (const float*)d_in[1];
    const float* Wq  = (const float*)d_in[2];
    const float* bq  = (const float*)d_in[3];
    const float* Wk  = (const float*)d_in[4];
    const float* bk  = (const float*)d_in[5];
    float* out = (float*)d_out;

    char* ws = (char*)d_ws;
    unsigned short* Qhi = (unsigned short*)ws;                        // 4 MB
    unsigned short* Qlo = (unsigned short*)(ws + ((size_t)4  << 20)); // 4 MB
    unsigned short* Kbl = (unsigned short*)(ws + ((size_t)8  << 20)); // 4 MB
    float* Wqt = (float*)(ws + ((size_t)12 << 20));                   // 64 KB
    float* Wkt = (float*)(ws + ((size_t)12 << 20) + (64u << 10));     // 64 KB

    transpose_w2<<<dim3(2, 2, 2), 256, 0, stream>>>(Wq, Wk, Wqt, Wkt);
    project_q<<<NROWS/8, 64, 0, stream>>>(x_c, Wqt, bq, Qhi, Qlo);
    project_k<<<NROWS/8, 64, 0, stream>>>(x_n, Wkt, bk, Kbl);
    attn_entmax_mfma<<<NROWS/32, 256, 0, stream>>>(
        (const __bf16*)Qhi, (const __bf16*)Qlo, (const __bf16*)Kbl, out);
}

// Round 7
// 222.236 us; speedup vs baseline: 1.6639x; 1.6639x over previous
//
#include <hip/hip_runtime.h>
#include <hip/hip_bf16.h>

#define BATCH 8
#define SEQ   2048
#define DIM   128
#define NROWS 16384                       // BATCH*SEQ
#define INV_2SQRTD 0.04419417382415922f   // 1/(2*sqrt(128));  c^2 = 1/512 exact
#define THETA_SPAN 22.62741699796952f     // 1/c

typedef __bf16    bf16x8   __attribute__((ext_vector_type(8)));
typedef float     floatx16 __attribute__((ext_vector_type(16)));
typedef _Float16  half8    __attribute__((ext_vector_type(8)));

static __device__ __forceinline__ unsigned short f2bf(float v) {
    union { __hip_bfloat16 h; unsigned short u; } c;
    c.h = __float2bfloat16(v);
    return c.u;
}
static __device__ __forceinline__ float bf2f(unsigned short u) {
    union { unsigned int i; float f; } c;
    c.i = (unsigned int)u << 16;
    return c.f;
}

// ---------------------------------------------------------------------------
// Projection kernels. 32 rows/block, 256 threads. W transposed into LDS
// (no separate transpose kernel), X chunk in LDS, two e-phases of 64.
// Thread (l = tid&15, kthi = tid>>4) computes rows row0+l+16*rr (rr<2),
// cols d = kthi*8 + j -> stores are lane-contiguous 16B (coalesced), fixing
// round-5's scattered 4B stores.
// ---------------------------------------------------------------------------
__global__ void __launch_bounds__(256, 2)
project_q(const float* __restrict__ X, const float* __restrict__ W,
          const float* __restrict__ bias,
          unsigned short* __restrict__ Qhi, unsigned short* __restrict__ Qlo) {
    __shared__ float wt[64][132];   // wt[e'][d]
    __shared__ float xs[32][68];    // xs[r][e']
    const int tid  = threadIdx.x;
    const int l    = tid & 15;
    const int kthi = tid >> 4;
    const int row0 = blockIdx.x * 32;

    float s[2][8];
#pragma unroll
    for (int rr = 0; rr < 2; ++rr)
#pragma unroll
        for (int j = 0; j < 8; ++j) s[rr][j] = 0.0f;

    for (int ph = 0; ph < 2; ++ph) {
        const int e0 = ph * 64;
        // stage W[d][e0+e'] -> wt[e'][d]  (global gather; tiny: 32KB/phase)
#pragma unroll
        for (int i = 0; i < 8; ++i) {
            const int f  = tid + 256 * i;          // f < 2048
            const int d  = f & 127;
            const int c4 = f >> 7;                 // 0..15
            float4 wv = *reinterpret_cast<const float4*>(
                W + (size_t)d * DIM + e0 + 4 * c4);
            wt[4*c4+0][d] = wv.x;  wt[4*c4+1][d] = wv.y;
            wt[4*c4+2][d] = wv.z;  wt[4*c4+3][d] = wv.w;
        }
        // stage X[row0+r][e0+e'] -> xs[r][e']  (coalesced)
#pragma unroll
        for (int i = 0; i < 2; ++i) {
            const int f  = tid + 256 * i;          // f < 512
            const int r  = f >> 4;
            const int c4 = f & 15;
            float4 xv = *reinterpret_cast<const float4*>(
                X + (size_t)(row0 + r) * DIM + e0 + 4 * c4);
            *reinterpret_cast<float4*>(&xs[r][4 * c4]) = xv;
        }
        __syncthreads();
#pragma unroll 8
        for (int e = 0; e < 64; ++e) {
            float w8[8];
            *reinterpret_cast<float4*>(w8)     =
                *reinterpret_cast<const float4*>(&wt[e][kthi * 8]);
            *reinterpret_cast<float4*>(w8 + 4) =
                *reinterpret_cast<const float4*>(&wt[e][kthi * 8 + 4]);
#pragma unroll
            for (int rr = 0; rr < 2; ++rr) {
                const float xv = xs[l + 16 * rr][e];
#pragma unroll
                for (int j = 0; j < 8; ++j) s[rr][j] = fmaf(xv, w8[j], s[rr][j]);
            }
        }
        __syncthreads();
    }

    float b8[8];
    *reinterpret_cast<float4*>(b8)     = *reinterpret_cast<const float4*>(bias + kthi * 8);
    *reinterpret_cast<float4*>(b8 + 4) = *reinterpret_cast<const float4*>(bias + kthi * 8 + 4);
#pragma unroll
    for (int rr = 0; rr < 2; ++rr) {
        const int row = row0 + l + 16 * rr;
        union { uint4 v; unsigned short u[8]; } ph, pl;
#pragma unroll
        for (int j = 0; j < 8; ++j) {
            const float v = s[rr][j] + b8[j];
            const unsigned short h = f2bf(v);
            ph.u[j] = h;
            pl.u[j] = f2bf(v - bf2f(h));
        }
        const size_t base = ((size_t)kthi * NROWS + row) * 8;
        *reinterpret_cast<uint4*>(Qhi + base) = ph.v;
        *reinterpret_cast<uint4*>(Qlo + base) = pl.v;
    }
}

__global__ void __launch_bounds__(256, 2)
project_k(const float* __restrict__ X, const float* __restrict__ W,
          const float* __restrict__ bias, unsigned short* __restrict__ Kb) {
    __shared__ float wt[64][132];
    __shared__ float xs[32][68];
    const int tid  = threadIdx.x;
    const int l    = tid & 15;
    const int kthi = tid >> 4;
    const int row0 = blockIdx.x * 32;

    float s[2][8];
#pragma unroll
    for (int rr = 0; rr < 2; ++rr)
#pragma unroll
        for (int j = 0; j < 8; ++j) s[rr][j] = 0.0f;

    for (int ph = 0; ph < 2; ++ph) {
        const int e0 = ph * 64;
#pragma unroll
        for (int i = 0; i < 8; ++i) {
            const int f  = tid + 256 * i;
            const int d  = f & 127;
            const int c4 = f >> 7;
            float4 wv = *reinterpret_cast<const float4*>(
                W + (size_t)d * DIM + e0 + 4 * c4);
            wt[4*c4+0][d] = wv.x;  wt[4*c4+1][d] = wv.y;
            wt[4*c4+2][d] = wv.z;  wt[4*c4+3][d] = wv.w;
        }
#pragma unroll
        for (int i = 0; i < 2; ++i) {
            const int f  = tid + 256 * i;
            const int r  = f >> 4;
            const int c4 = f & 15;
            float4 xv = *reinterpret_cast<const float4*>(
                X + (size_t)(row0 + r) * DIM + e0 + 4 * c4);
            *reinterpret_cast<float4*>(&xs[r][4 * c4]) = xv;
        }
        __syncthreads();
#pragma unroll 8
        for (int e = 0; e < 64; ++e) {
            float w8[8];
            *reinterpret_cast<float4*>(w8)     =
                *reinterpret_cast<const float4*>(&wt[e][kthi * 8]);
            *reinterpret_cast<float4*>(w8 + 4) =
                *reinterpret_cast<const float4*>(&wt[e][kthi * 8 + 4]);
#pragma unroll
            for (int rr = 0; rr < 2; ++rr) {
                const float xv = xs[l + 16 * rr][e];
#pragma unroll
                for (int j = 0; j < 8; ++j) s[rr][j] = fmaf(xv, w8[j], s[rr][j]);
            }
        }
        __syncthreads();
    }

    float b8[8];
    *reinterpret_cast<float4*>(b8)     = *reinterpret_cast<const float4*>(bias + kthi * 8);
    *reinterpret_cast<float4*>(b8 + 4) = *reinterpret_cast<const float4*>(bias + kthi * 8 + 4);
#pragma unroll
    for (int rr = 0; rr < 2; ++rr) {
        const int row = row0 + l + 16 * rr;
        const int b   = row >> 11;
        const int key = row & (SEQ - 1);
        union { uint4 v; unsigned short u[8]; } pk;
#pragma unroll
        for (int j = 0; j < 8; ++j) pk.u[j] = f2bf(s[rr][j] + b8[j]);
        const size_t base = (((size_t)(b * 16) + kthi) * SEQ + key) * 8;
        *reinterpret_cast<uint4*>(Kb + base) = pk.v;
    }
}

// ---------------------------------------------------------------------------
// k1: MFMA score GEMM -> raw scores f16, S[row][key].
// Block: 32 rows x 512 keys, 4 waves (wave = 4 x 32x32 key-tiles -> only
// 64 acc VGPRs: ~4 waves/SIMD vs round-5's 2). Grid (512 row-blks, 4 key-blks):
// x-fastest dispatch keeps each key-slice L2-hot.
// ---------------------------------------------------------------------------
__global__ void __launch_bounds__(256, 2)
score_gemm(const __bf16* __restrict__ Qhi, const __bf16* __restrict__ Qlo,
           const __bf16* __restrict__ Kb, _Float16* __restrict__ S) {
    const int tid  = threadIdx.x;
    const int wv   = tid >> 6;
    const int lane = tid & 63;
    const int l5   = lane & 31;
    const int hi5  = lane >> 5;
    const int row0 = blockIdx.x * 32;
    const int b    = row0 >> 11;
    const int key0 = blockIdx.y * 512 + wv * 128;

    floatx16 acc[4];
    const floatx16 zerov = {};
#pragma unroll
    for (int t = 0; t < 4; ++t) acc[t] = zerov;

    const __bf16* qh = Qhi + ((size_t)hi5 * NROWS + row0 + l5) * 8;
    const __bf16* ql = Qlo + ((size_t)hi5 * NROWS + row0 + l5) * 8;
    const __bf16* kp = Kb + (((size_t)(b * 16) + hi5) * SEQ + key0 + l5) * 8;
    const size_t qstep = (size_t)2 * NROWS * 8;
    const size_t kstep = (size_t)2 * SEQ * 8;

#pragma unroll
    for (int kt = 0; kt < 8; ++kt) {
        const bf16x8 ah = *reinterpret_cast<const bf16x8*>(qh + kt * qstep);
        const bf16x8 al = *reinterpret_cast<const bf16x8*>(ql + kt * qstep);
        const __bf16* kc = kp + kt * kstep;
#pragma unroll
        for (int t = 0; t < 4; ++t) {
            const bf16x8 bk = *reinterpret_cast<const bf16x8*>(kc + (size_t)t * 256);
            acc[t] = __builtin_amdgcn_mfma_f32_32x32x16_bf16(ah, bk, acc[t], 0, 0, 0);
            acc[t] = __builtin_amdgcn_mfma_f32_32x32x16_bf16(al, bk, acc[t], 0, 0, 0);
        }
    }
    // C layout (m74/m101): col = l5, row = (r&3) + 8*(r>>2) + 4*hi5
#pragma unroll
    for (int t = 0; t < 4; ++t) {
#pragma unroll
        for (int r = 0; r < 16; ++r) {
            const int rowl = (r & 3) + 8 * (r >> 2) + 4 * hi5;
            S[(size_t)(row0 + rowl) * SEQ + key0 + t * 32 + l5] =
                (_Float16)acc[t][r];
        }
    }
}

// ---------------------------------------------------------------------------
// k2: exact 1.5-entmax per row. ONE WAVE PER ROW (no __syncthreads at all);
// lane owns keys {k*512 + lane*8 + i}. Bisection done in raw-score space:
// theta* s.t. sum max(s-theta,0)^2 = 512  (c^2 = 1/512 exact), theta in
// [smax - 1/c, smax]. 12 iters -> tau err ~6e-5. p = max(s-theta,0)^2 / 512.
// ---------------------------------------------------------------------------
__global__ void __launch_bounds__(256, 4)
entmax_rows(const _Float16* __restrict__ S, float* __restrict__ out) {
    const int lane = threadIdx.x & 63;
    const int row  = blockIdx.x * 4 + (threadIdx.x >> 6);

    const uint4* srow = reinterpret_cast<const uint4*>(S + (size_t)row * SEQ);
    float z[32];
#pragma unroll
    for (int k = 0; k < 4; ++k) {
        union { uint4 u; half8 h; } cv;
        cv.u = srow[k * 64 + lane];        // 1KB contiguous per wave-instr
#pragma unroll
        for (int i = 0; i < 8; ++i) z[k * 8 + i] = (float)cv.h[i];
    }

    // row max
    float m = z[0];
#pragma unroll
    for (int i = 1; i < 32; ++i) m = fmaxf(m, z[i]);
#pragma unroll
    for (int off = 32; off >= 1; off >>= 1) m = fmaxf(m, __shfl_xor(m, off, 64));

    float lo = m - THETA_SPAN, hi = m;
    for (int it = 0; it < 12; ++it) {
        const float th = 0.5f * (lo + hi);
        float f0 = 0.0f, f1 = 0.0f, f2 = 0.0f, f3 = 0.0f;
#pragma unroll
        for (int i = 0; i < 8; ++i) {
            const float a0 = fmaxf(z[4 * i + 0] - th, 0.0f);
            const float a1 = fmaxf(z[4 * i + 1] - th, 0.0f);
            const float a2 = fmaxf(z[4 * i + 2] - th, 0.0f);
            const float a3 = fmaxf(z[4 * i + 3] - th, 0.0f);
            f0 = fmaf(a0, a0, f0); f1 = fmaf(a1, a1, f1);
            f2 = fmaf(a2, a2, f2); f3 = fmaf(a3, a3, f3);
        }
        float fs = (f0 + f1) + (f2 + f3);
#pragma unroll
        for (int off = 32; off >= 1; off >>= 1) fs += __shfl_xor(fs, off, 64);
        if (fs >= 512.0f) lo = th; else hi = th;
    }
    const float th = 0.5f * (lo + hi);

    float* orow = out + (size_t)row * SEQ;
#pragma unroll
    for (int k = 0; k < 4; ++k) {
        float pv[8];
#pragma unroll
        for (int i = 0; i < 8; ++i) {
            const float d = fmaxf(z[k * 8 + i] - th, 0.0f);
            pv[i] = d * d * (1.0f / 512.0f);
        }
        float* op = orow + k * 512 + lane * 8;
        *reinterpret_cast<float4*>(op)     = make_float4(pv[0], pv[1], pv[2], pv[3]);
        *reinterpret_cast<float4*>(op + 4) = make_float4(pv[4], pv[5], pv[6], pv[7]);
    }
}

// ---------------------------------------------------------------------------
// Fallback (ws too small for the 67MB S buffer): round-5 fused kernel,
// correctness-proven at 218us.
// ---------------------------------------------------------------------------
__global__ void __launch_bounds__(256, 1)
attn_entmax_mfma(const __bf16* __restrict__ Qhi, const __bf16* __restrict__ Qlo,
                 const __bf16* __restrict__ Kb, float* __restrict__ out) {
    const int tid  = threadIdx.x;
    const int wv   = tid >> 6;
    const int lane = tid & 63;
    const int l5   = lane & 31;
    const int hi5  = lane >> 5;
    const int row0 = blockIdx.x * 32;
    const int b    = row0 >> 11;
    const int key0 = wv * 512;

    floatx16 acc[16];
    const floatx16 zerov = {};
#pragma unroll
    for (int t = 0; t < 16; ++t) acc[t] = zerov;

    const __bf16* Kbase = Kb + (size_t)b * (8 * 2 * SEQ * 8);
#pragma unroll
    for (int kt = 0; kt < 8; ++kt) {
        const size_t qoff = (((size_t)kt * 2 + hi5) * NROWS + row0 + l5) * 8;
        const bf16x8 ah = *reinterpret_cast<const bf16x8*>(Qhi + qoff);
        const bf16x8 al = *reinterpret_cast<const bf16x8*>(Qlo + qoff);
        const __bf16* kp = Kbase + (((size_t)kt * 2 + hi5) * SEQ + key0 + l5) * 8;
#pragma unroll
        for (int t = 0; t < 16; ++t) {
            const bf16x8 bk = *reinterpret_cast<const bf16x8*>(kp + (size_t)t * 32 * 8);
            acc[t] = __builtin_amdgcn_mfma_f32_32x32x16_bf16(ah, bk, acc[t], 0, 0, 0);
            acc[t] = __builtin_amdgcn_mfma_f32_32x32x16_bf16(al, bk, acc[t], 0, 0, 0);
        }
    }
    __shared__ __align__(16) float red[32][4];
    float rm[16];
#pragma unroll
    for (int r = 0; r < 16; ++r) {
        float m = acc[0][r];
#pragma unroll
        for (int t = 1; t < 16; ++t) m = fmaxf(m, acc[t][r]);
#pragma unroll
        for (int off = 16; off >= 1; off >>= 1) m = fmaxf(m, __shfl_xor(m, off, 64));
        if (l5 == r) red[(r & 3) + 8 * (r >> 2) + 4 * hi5][wv] = m;
    }
    __syncthreads();
#pragma unroll
    for (int r = 0; r < 16; ++r) {
        const int rowl = (r & 3) + 8 * (r >> 2) + 4 * hi5;
        const float4 mv = *reinterpret_cast<const float4*>(red[rowl]);
        rm[r] = fmaxf(fmaxf(mv.x, mv.y), fmaxf(mv.z, mv.w));
    }
    __syncthreads();
#pragma unroll
    for (int r = 0; r < 16; ++r) {
        const float nm = -rm[r] * INV_2SQRTD;
#pragma unroll
        for (int t = 0; t < 16; ++t) acc[t][r] = fmaf(acc[t][r], INV_2SQRTD, nm);
    }
    float lo[16], hh[16];
#pragma unroll
    for (int r = 0; r < 16; ++r) { lo[r] = -1.0f; hh[r] = 0.0f; }
    for (int it = 0; it < 14; ++it) {
#pragma unroll
        for (int r = 0; r < 16; ++r) {
            const float tau = 0.5f * (lo[r] + hh[r]);
            float f = 0.0f;
#pragma unroll
            for (int t = 0; t < 16; ++t) {
                const float d = fmaxf(acc[t][r] - tau, 0.0f);
                f = fmaf(d, d, f);
            }
#pragma unroll
            for (int off = 16; off >= 1; off >>= 1) f += __shfl_xor(f, off, 64);
            if (l5 == r) red[(r & 3) + 8 * (r >> 2) + 4 * hi5][wv] = f;
        }
        __syncthreads();
#pragma unroll
        for (int r = 0; r < 16; ++r) {
            const int rowl = (r & 3) + 8 * (r >> 2) + 4 * hi5;
            const float4 fv = *reinterpret_cast<const float4*>(red[rowl]);
            const float fs = (fv.x + fv.y) + (fv.z + fv.w);
            const float tau = 0.5f * (lo[r] + hh[r]);
            if (fs >= 1.0f) lo[r] = tau; else hh[r] = tau;
        }
        __syncthreads();
    }
#pragma unroll
    for (int r = 0; r < 16; ++r) {
        const int rowl = (r & 3) + 8 * (r >> 2) + 4 * hi5;
        const float tau = 0.5f * (lo[r] + hh[r]);
        float* op = out + (size_t)(row0 + rowl) * SEQ + key0 + l5;
#pragma unroll
        for (int t = 0; t < 16; ++t) {
            const float d = fmaxf(acc[t][r] - tau, 0.0f);
            op[(size_t)t * 32] = d * d;
        }
    }
}

// ---------------------------------------------------------------------------
extern "C" void kernel_launch(void* const* d_in, const int* in_sizes, int n_in,
                              void* d_out, int out_size, void* d_ws, size_t ws_size,
                              hipStream_t stream) {
    const float* x_c = (const float*)d_in[0];
    const float* x_n = (const float*)d_in[1];
    const float* Wq  = (const float*)d_in[2];
    const float* bq  = (const float*)d_in[3];
    const float* Wk  = (const float*)d_in[4];
    const float* bk  = (const float*)d_in[5];
    float* out = (float*)d_out;

    char* ws = (char*)d_ws;
    unsigned short* Qhi = (unsigned short*)ws;                        // 4 MB
    unsigned short* Qlo = (unsigned short*)(ws + ((size_t)4 << 20));  // 4 MB
    unsigned short* Kbl = (unsigned short*)(ws + ((size_t)8 << 20));  // 4 MB
    _Float16*       S   = (_Float16*)(ws + ((size_t)12 << 20));       // 67 MB

    const size_t need = ((size_t)12 << 20) + (size_t)NROWS * SEQ * 2;

    project_q<<<NROWS / 32, 256, 0, stream>>>(x_c, Wq, bq, Qhi, Qlo);
    project_k<<<NROWS / 32, 256, 0, stream>>>(x_n, Wk, bk, Kbl);

    if (ws_size >= need) {
        score_gemm<<<dim3(NROWS / 32, 4), 256, 0, stream>>>(
            (const __bf16*)Qhi, (const __bf16*)Qlo, (const __bf16*)Kbl, S);
        entmax_rows<<<NROWS / 4, 256, 0, stream>>>(S, out);
    } else {
        attn_entmax_mfma<<<NROWS / 32, 256, 0, stream>>>(
            (const __bf16*)Qhi, (const __bf16*)Qlo, (const __bf16*)Kbl, out);
    }
}

// Round 8
// 209.326 us; speedup vs baseline: 1.7665x; 1.0617x over previous
//
#include <hip/hip_runtime.h>
#include <hip/hip_bf16.h>

#define BATCH 8
#define SEQ   2048
#define DIM   128
#define NROWS 16384                       // BATCH*SEQ
#define THETA_SPAN 22.62741699796952f     // 2*sqrt(128) = 1/c ; c^2 = 1/512

typedef __bf16    bf16x8   __attribute__((ext_vector_type(8)));
typedef float     floatx16 __attribute__((ext_vector_type(16)));

static __device__ __forceinline__ unsigned short f2bf(float v) {
    union { __hip_bfloat16 h; unsigned short u; } c;
    c.h = __float2bfloat16(v);
    return c.u;
}
static __device__ __forceinline__ float bf2f(unsigned short u) {
    union { unsigned int i; float f; } c;
    c.i = (unsigned int)u << 16;
    return c.f;
}
static __device__ __forceinline__ unsigned short f2h(float v) {
    union { _Float16 h; unsigned short u; } c;
    c.h = (_Float16)v;
    return c.u;
}
static __device__ __forceinline__ float h2f(unsigned short u) {
    union { _Float16 h; unsigned short u; } c;
    c.u = u;
    return (float)c.h;
}

// ---------------------------------------------------------------------------
// Merged Q/K projection. grid (NROWS/64, 2): y=0 -> Q (hi/lo bf16 split),
// y=1 -> K (bf16). 64 rows/block, 256 threads, two 64-wide e-phases.
// W staged coalesced (consecutive lanes -> consecutive float4 within a W row)
// and transposed into LDS [e][d] with +5 pad (133) to break bank conflicts.
// Thread (l=tid&15, kthi=tid>>4) computes rows l+16*rr (rr<4), cols kthi*8+j.
// Output layouts match score_gemm fragment order:
//   Q: [(kthi)*NROWS + row]*8 + j   (kthi = kt*2 + hi)
//   K: [(b*16 + kthi)*SEQ + key]*8 + j
// ---------------------------------------------------------------------------
__global__ void __launch_bounds__(256)
proj_qk(const float* __restrict__ xq, const float* __restrict__ xn,
        const float* __restrict__ Wq, const float* __restrict__ bq,
        const float* __restrict__ Wk, const float* __restrict__ bk,
        unsigned short* __restrict__ Qhi, unsigned short* __restrict__ Qlo,
        unsigned short* __restrict__ Kb) {
    const int isK = blockIdx.y;
    const float* __restrict__ X    = isK ? xn : xq;
    const float* __restrict__ W    = isK ? Wk : Wq;
    const float* __restrict__ bias = isK ? bk : bq;

    __shared__ float wt[64][133];   // wt[e'][d]
    __shared__ float xs[64][68];    // xs[r][e']
    const int tid  = threadIdx.x;
    const int l    = tid & 15;
    const int kthi = tid >> 4;
    const int row0 = blockIdx.x * 64;

    float s[4][8];
#pragma unroll
    for (int rr = 0; rr < 4; ++rr)
#pragma unroll
        for (int j = 0; j < 8; ++j) s[rr][j] = 0.0f;

    for (int ph = 0; ph < 2; ++ph) {
        const int e0 = ph * 64;
        // stage W half (128 d x 64 e): coalesced within W rows
#pragma unroll
        for (int i = 0; i < 8; ++i) {
            const int g  = tid + 256 * i;          // g < 2048
            const int d  = g >> 4;
            const int c4 = g & 15;
            float4 wv = *reinterpret_cast<const float4*>(
                W + (size_t)d * DIM + e0 + 4 * c4);
            wt[4*c4+0][d] = wv.x;  wt[4*c4+1][d] = wv.y;
            wt[4*c4+2][d] = wv.z;  wt[4*c4+3][d] = wv.w;
        }
        // stage X (64 rows x 64 e): coalesced
#pragma unroll
        for (int i = 0; i < 4; ++i) {
            const int g  = tid + 256 * i;          // g < 1024
            const int r  = g >> 4;
            const int c4 = g & 15;
            float4 xv = *reinterpret_cast<const float4*>(
                X + (size_t)(row0 + r) * DIM + e0 + 4 * c4);
            *reinterpret_cast<float4*>(&xs[r][4 * c4]) = xv;
        }
        __syncthreads();
#pragma unroll 8
        for (int e = 0; e < 64; ++e) {
            float w8[8];
            *reinterpret_cast<float4*>(w8)     =
                *reinterpret_cast<const float4*>(&wt[e][kthi * 8]);
            *reinterpret_cast<float4*>(w8 + 4) =
                *reinterpret_cast<const float4*>(&wt[e][kthi * 8 + 4]);
#pragma unroll
            for (int rr = 0; rr < 4; ++rr) {
                const float xv = xs[l + 16 * rr][e];
#pragma unroll
                for (int j = 0; j < 8; ++j) s[rr][j] = fmaf(xv, w8[j], s[rr][j]);
            }
        }
        __syncthreads();
    }

    float b8[8];
    *reinterpret_cast<float4*>(b8)     = *reinterpret_cast<const float4*>(bias + kthi * 8);
    *reinterpret_cast<float4*>(b8 + 4) = *reinterpret_cast<const float4*>(bias + kthi * 8 + 4);

    if (!isK) {
#pragma unroll
        for (int rr = 0; rr < 4; ++rr) {
            const int row = row0 + l + 16 * rr;
            union { uint4 v; unsigned short u[8]; } ph_, pl_;
#pragma unroll
            for (int j = 0; j < 8; ++j) {
                const float v = s[rr][j] + b8[j];
                const unsigned short h = f2bf(v);
                ph_.u[j] = h;
                pl_.u[j] = f2bf(v - bf2f(h));
            }
            const size_t base = ((size_t)kthi * NROWS + row) * 8;
            *reinterpret_cast<uint4*>(Qhi + base) = ph_.v;
            *reinterpret_cast<uint4*>(Qlo + base) = pl_.v;
        }
    } else {
#pragma unroll
        for (int rr = 0; rr < 4; ++rr) {
            const int row = row0 + l + 16 * rr;
            const int b   = row >> 11;
            const int key = row & (SEQ - 1);
            union { uint4 v; unsigned short u[8]; } pk;
#pragma unroll
            for (int j = 0; j < 8; ++j) pk.u[j] = f2bf(s[rr][j] + b8[j]);
            const size_t base = (((size_t)(b * 16) + kthi) * SEQ + key) * 8;
            *reinterpret_cast<uint4*>(Kb + base) = pk.v;
        }
    }
}

// ---------------------------------------------------------------------------
// k1: MFMA score GEMM -> raw scores f16, packed 4-rows-per-element:
// S4[rowgroup][key] is a uint2 holding f16 scores of rows {rowgroup*4..+3}.
// Block: 32 rows x 512 keys, 4 waves, acc 4x16 (64 VGPRs).
// C layout (m74/m101): col=l5, row=(r&3)+8*(r>>2)+4*hi5 -> a reg-quad
// {4a..4a+3} is 4 consecutive rows -> one uint2 store (256B/half-wave).
// ---------------------------------------------------------------------------
__global__ void __launch_bounds__(256, 3)
score_gemm(const __bf16* __restrict__ Qhi, const __bf16* __restrict__ Qlo,
           const __bf16* __restrict__ Kb, uint2* __restrict__ S4) {
    const int tid  = threadIdx.x;
    const int wv   = tid >> 6;
    const int lane = tid & 63;
    const int l5   = lane & 31;
    const int hi5  = lane >> 5;
    const int row0 = blockIdx.x * 32;
    const int b    = row0 >> 11;
    const int key0 = blockIdx.y * 512 + wv * 128;

    floatx16 acc[4];
    const floatx16 zerov = {};
#pragma unroll
    for (int t = 0; t < 4; ++t) acc[t] = zerov;

    const __bf16* qh = Qhi + ((size_t)hi5 * NROWS + row0 + l5) * 8;
    const __bf16* ql = Qlo + ((size_t)hi5 * NROWS + row0 + l5) * 8;
    const __bf16* kp = Kb + (((size_t)(b * 16) + hi5) * SEQ + key0 + l5) * 8;
    const size_t qstep = (size_t)2 * NROWS * 8;
    const size_t kstep = (size_t)2 * SEQ * 8;

#pragma unroll
    for (int kt = 0; kt < 8; ++kt) {
        const bf16x8 ah = *reinterpret_cast<const bf16x8*>(qh + kt * qstep);
        const bf16x8 al = *reinterpret_cast<const bf16x8*>(ql + kt * qstep);
        const __bf16* kc = kp + kt * kstep;
#pragma unroll
        for (int t = 0; t < 4; ++t) {
            const bf16x8 bkv = *reinterpret_cast<const bf16x8*>(kc + (size_t)t * 256);
            acc[t] = __builtin_amdgcn_mfma_f32_32x32x16_bf16(ah, bkv, acc[t], 0, 0, 0);
            acc[t] = __builtin_amdgcn_mfma_f32_32x32x16_bf16(al, bkv, acc[t], 0, 0, 0);
        }
    }

#pragma unroll
    for (int t = 0; t < 4; ++t) {
#pragma unroll
        for (int a = 0; a < 4; ++a) {
            const int rowgroup = (row0 >> 2) + 2 * a + hi5;
            union { uint2 v; unsigned short u[4]; } pk;
#pragma unroll
            for (int bb = 0; bb < 4; ++bb) pk.u[bb] = f2h(acc[t][4 * a + bb]);
            S4[(size_t)rowgroup * SEQ + key0 + t * 32 + l5] = pk.v;
        }
    }
}

// ---------------------------------------------------------------------------
// k2: exact 1.5-entmax per row. One wave per row, 4 rows (= 1 rowgroup) per
// block so all 4 waves stream the SAME S4 lines (L1/L2 serve 3 of 4).
// Lane owns keys {c*64 + lane}: 8B uint2 loads and 4B f32 stores are
// perfectly lane-contiguous. Bisection in raw-score space:
// sum max(s-theta,0)^2 = 512 (c^2=1/512 exact), theta in [smax-1/c, smax],
// 12 iters -> theta err 5.5e-3 -> p err < 5e-4. No __syncthreads anywhere.
// ---------------------------------------------------------------------------
__global__ void __launch_bounds__(256, 4)
entmax_rows(const uint2* __restrict__ S4, float* __restrict__ out) {
    const int lane = threadIdx.x & 63;
    const int w    = threadIdx.x >> 6;
    const int row  = blockIdx.x * 4 + w;       // 4 rows = one rowgroup
    const int sub  = row & 3;                  // wave-uniform

    const uint2* sp = S4 + (size_t)(row >> 2) * SEQ;
    float z[32];
#pragma unroll
    for (int c = 0; c < 32; ++c) {
        const uint2 v = sp[c * 64 + lane];
        const unsigned int word = (sub & 2) ? v.y : v.x;
        const unsigned short h  = (sub & 1) ? (unsigned short)(word >> 16)
                                            : (unsigned short)(word & 0xffffu);
        z[c] = h2f(h);
    }

    // row max
    float m = z[0];
#pragma unroll
    for (int i = 1; i < 32; ++i) m = fmaxf(m, z[i]);
#pragma unroll
    for (int off = 32; off >= 1; off >>= 1) m = fmaxf(m, __shfl_xor(m, off, 64));

    float lo = m - THETA_SPAN, hi = m;
    for (int it = 0; it < 12; ++it) {
        const float th = 0.5f * (lo + hi);
        float f0 = 0.0f, f1 = 0.0f, f2 = 0.0f, f3 = 0.0f;
#pragma unroll
        for (int i = 0; i < 8; ++i) {
            const float a0 = fmaxf(z[4 * i + 0] - th, 0.0f);
            const float a1 = fmaxf(z[4 * i + 1] - th, 0.0f);
            const float a2 = fmaxf(z[4 * i + 2] - th, 0.0f);
            const float a3 = fmaxf(z[4 * i + 3] - th, 0.0f);
            f0 = fmaf(a0, a0, f0); f1 = fmaf(a1, a1, f1);
            f2 = fmaf(a2, a2, f2); f3 = fmaf(a3, a3, f3);
        }
        float fs = (f0 + f1) + (f2 + f3);
#pragma unroll
        for (int off = 32; off >= 1; off >>= 1) fs += __shfl_xor(fs, off, 64);
        if (fs >= 512.0f) lo = th; else hi = th;
    }
    const float th = 0.5f * (lo + hi);

    float* orow = out + (size_t)row * SEQ;
#pragma unroll
    for (int c = 0; c < 32; ++c) {
        const float d = fmaxf(z[c] - th, 0.0f);
        orow[c * 64 + lane] = d * d * (1.0f / 512.0f);
    }
}

// ---------------------------------------------------------------------------
extern "C" void kernel_launch(void* const* d_in, const int* in_sizes, int n_in,
                              void* d_out, int out_size, void* d_ws, size_t ws_size,
                              hipStream_t stream) {
    const float* x_c = (const float*)d_in[0];
    const float* x_n = (const float*)d_in[1];
    const float* Wq  = (const float*)d_in[2];
    const float* bq  = (const float*)d_in[3];
    const float* Wk  = (const float*)d_in[4];
    const float* bk  = (const float*)d_in[5];
    float* out = (float*)d_out;

    char* ws = (char*)d_ws;
    unsigned short* Qhi = (unsigned short*)ws;                        // 4 MB
    unsigned short* Qlo = (unsigned short*)(ws + ((size_t)4 << 20));  // 4 MB
    unsigned short* Kbl = (unsigned short*)(ws + ((size_t)8 << 20));  // 4 MB
    uint2*          S4  = (uint2*)(ws + ((size_t)12 << 20));          // 67 MB

    proj_qk<<<dim3(NROWS / 64, 2), 256, 0, stream>>>(
        x_c, x_n, Wq, bq, Wk, bk, Qhi, Qlo, Kbl);
    score_gemm<<<dim3(NROWS / 32, 4), 256, 0, stream>>>(
        (const __bf16*)Qhi, (const __bf16*)Qlo, (const __bf16*)Kbl, S4);
    entmax_rows<<<NROWS / 4, 256, 0, stream>>>(S4, out);
}

// Round 9
// 200.651 us; speedup vs baseline: 1.8429x; 1.0432x over previous
//
#include <hip/hip_runtime.h>
#include <hip/hip_bf16.h>

#define BATCH 8
#define SEQ   2048
#define DIM   128
#define NROWS 16384                       // BATCH*SEQ
#define THETA_SPAN 22.62741699796952f     // 2*sqrt(128) = 1/c ; c^2 = 1/512

typedef __bf16    bf16x8   __attribute__((ext_vector_type(8)));
typedef float     floatx16 __attribute__((ext_vector_type(16)));
typedef _Float16  half2v   __attribute__((ext_vector_type(2)));

static __device__ __forceinline__ unsigned short f2bf(float v) {
    union { __hip_bfloat16 h; unsigned short u; } c;
    c.h = __float2bfloat16(v);
    return c.u;
}
static __device__ __forceinline__ float bf2f(unsigned short u) {
    union { unsigned int i; float f; } c;
    c.i = (unsigned int)u << 16;
    return c.f;
}
static __device__ __forceinline__ unsigned short f2h(float v) {
    union { _Float16 h; unsigned short u; } c;
    c.h = (_Float16)v;
    return c.u;
}

#if __has_builtin(__builtin_amdgcn_fdot2)
static __device__ __forceinline__ float fdot2acc(half2v a, half2v b, float c) {
    return __builtin_amdgcn_fdot2(a, b, c, false);
}
#else
static __device__ __forceinline__ float fdot2acc(half2v a, half2v b, float c) {
    return fmaf((float)a.y, (float)b.y, fmaf((float)a.x, (float)b.x, c));
}
#endif

// ---------------------------------------------------------------------------
// Merged Q/K projection (unchanged from round 8 — verified).
// grid (NROWS/64, 2): y=0 -> Q (hi/lo bf16 split), y=1 -> K (bf16).
// ---------------------------------------------------------------------------
__global__ void __launch_bounds__(256)
proj_qk(const float* __restrict__ xq, const float* __restrict__ xn,
        const float* __restrict__ Wq, const float* __restrict__ bq,
        const float* __restrict__ Wk, const float* __restrict__ bk,
        unsigned short* __restrict__ Qhi, unsigned short* __restrict__ Qlo,
        unsigned short* __restrict__ Kb) {
    const int isK = blockIdx.y;
    const float* __restrict__ X    = isK ? xn : xq;
    const float* __restrict__ W    = isK ? Wk : Wq;
    const float* __restrict__ bias = isK ? bk : bq;

    __shared__ float wt[64][133];   // wt[e'][d]
    __shared__ float xs[64][68];    // xs[r][e']
    const int tid  = threadIdx.x;
    const int l    = tid & 15;
    const int kthi = tid >> 4;
    const int row0 = blockIdx.x * 64;

    float s[4][8];
#pragma unroll
    for (int rr = 0; rr < 4; ++rr)
#pragma unroll
        for (int j = 0; j < 8; ++j) s[rr][j] = 0.0f;

    for (int ph = 0; ph < 2; ++ph) {
        const int e0 = ph * 64;
#pragma unroll
        for (int i = 0; i < 8; ++i) {
            const int g  = tid + 256 * i;          // g < 2048
            const int d  = g >> 4;
            const int c4 = g & 15;
            float4 wv = *reinterpret_cast<const float4*>(
                W + (size_t)d * DIM + e0 + 4 * c4);
            wt[4*c4+0][d] = wv.x;  wt[4*c4+1][d] = wv.y;
            wt[4*c4+2][d] = wv.z;  wt[4*c4+3][d] = wv.w;
        }
#pragma unroll
        for (int i = 0; i < 4; ++i) {
            const int g  = tid + 256 * i;          // g < 1024
            const int r  = g >> 4;
            const int c4 = g & 15;
            float4 xv = *reinterpret_cast<const float4*>(
                X + (size_t)(row0 + r) * DIM + e0 + 4 * c4);
            *reinterpret_cast<float4*>(&xs[r][4 * c4]) = xv;
        }
        __syncthreads();
#pragma unroll 8
        for (int e = 0; e < 64; ++e) {
            float w8[8];
            *reinterpret_cast<float4*>(w8)     =
                *reinterpret_cast<const float4*>(&wt[e][kthi * 8]);
            *reinterpret_cast<float4*>(w8 + 4) =
                *reinterpret_cast<const float4*>(&wt[e][kthi * 8 + 4]);
#pragma unroll
            for (int rr = 0; rr < 4; ++rr) {
                const float xv = xs[l + 16 * rr][e];
#pragma unroll
                for (int j = 0; j < 8; ++j) s[rr][j] = fmaf(xv, w8[j], s[rr][j]);
            }
        }
        __syncthreads();
    }

    float b8[8];
    *reinterpret_cast<float4*>(b8)     = *reinterpret_cast<const float4*>(bias + kthi * 8);
    *reinterpret_cast<float4*>(b8 + 4) = *reinterpret_cast<const float4*>(bias + kthi * 8 + 4);

    if (!isK) {
#pragma unroll
        for (int rr = 0; rr < 4; ++rr) {
            const int row = row0 + l + 16 * rr;
            union { uint4 v; unsigned short u[8]; } ph_, pl_;
#pragma unroll
            for (int j = 0; j < 8; ++j) {
                const float v = s[rr][j] + b8[j];
                const unsigned short h = f2bf(v);
                ph_.u[j] = h;
                pl_.u[j] = f2bf(v - bf2f(h));
            }
            const size_t base = ((size_t)kthi * NROWS + row) * 8;
            *reinterpret_cast<uint4*>(Qhi + base) = ph_.v;
            *reinterpret_cast<uint4*>(Qlo + base) = pl_.v;
        }
    } else {
#pragma unroll
        for (int rr = 0; rr < 4; ++rr) {
            const int row = row0 + l + 16 * rr;
            const int b   = row >> 11;
            const int key = row & (SEQ - 1);
            union { uint4 v; unsigned short u[8]; } pk;
#pragma unroll
            for (int j = 0; j < 8; ++j) pk.u[j] = f2bf(s[rr][j] + b8[j]);
            const size_t base = (((size_t)(b * 16) + kthi) * SEQ + key) * 8;
            *reinterpret_cast<uint4*>(Kb + base) = pk.v;
        }
    }
}

// ---------------------------------------------------------------------------
// FUSED scores + entmax. Block = 32 rows x 2048 keys, 16 waves (1024 thr),
// 1 block/CU (128KB LDS S-tile). Phase 1: wave wv computes the 32x128 key
// slice (round-8 score_gemm math, acc 4x16 = 64 VGPRs) and writes f16 scores
// to LDS in rowgroup packing: S4[g][key] = uint2 of rows {4g..4g+3}.
// One barrier. Phase 2: wave wv owns rowgroup wv>>1, sub-pair wv&1
// (rows 4g+2sp+{0,1}); lane loads the dword holding both sub-rows' halfwords
// (32 x ds_read_b32), v_perm extracts per-row f16x2 pairs; bisection for
// theta* (sum max(s-th,0)^2 = 512) in packed-f16 math:
// pk_add + pk_max + dot2_f32_f16 = 3 inst per 2 keys, 11 iters.
// theta f16-quantization err ~0.03 raw-units -> p err ~2e-3 (thr 1.1e-2).
// No cross-wave reduction anywhere after the single barrier.
// ---------------------------------------------------------------------------
__global__ void __launch_bounds__(1024, 4)
attn_fused(const __bf16* __restrict__ Qhi, const __bf16* __restrict__ Qlo,
           const __bf16* __restrict__ Kb, float* __restrict__ out) {
    __shared__ uint2 S4[8][SEQ];            // 128 KB
    const int tid  = threadIdx.x;
    const int wv   = tid >> 6;              // 0..15
    const int lane = tid & 63;
    const int l5   = lane & 31;
    const int hi5  = lane >> 5;
    const int row0 = blockIdx.x * 32;
    const int b    = row0 >> 11;
    const int key0 = wv * 128;

    // ---------------- phase 1: MFMA scores -> LDS ----------------
    {
        floatx16 acc[4];
        const floatx16 zerov = {};
#pragma unroll
        for (int t = 0; t < 4; ++t) acc[t] = zerov;

        const __bf16* qh = Qhi + ((size_t)hi5 * NROWS + row0 + l5) * 8;
        const __bf16* ql = Qlo + ((size_t)hi5 * NROWS + row0 + l5) * 8;
        const __bf16* kp = Kb + (((size_t)(b * 16) + hi5) * SEQ + key0 + l5) * 8;
        const size_t qstep = (size_t)2 * NROWS * 8;
        const size_t kstep = (size_t)2 * SEQ * 8;

#pragma unroll
        for (int kt = 0; kt < 8; ++kt) {
            const bf16x8 ah = *reinterpret_cast<const bf16x8*>(qh + kt * qstep);
            const bf16x8 al = *reinterpret_cast<const bf16x8*>(ql + kt * qstep);
            const __bf16* kc = kp + kt * kstep;
#pragma unroll
            for (int t = 0; t < 4; ++t) {
                const bf16x8 bkv = *reinterpret_cast<const bf16x8*>(kc + (size_t)t * 256);
                acc[t] = __builtin_amdgcn_mfma_f32_32x32x16_bf16(ah, bkv, acc[t], 0, 0, 0);
                acc[t] = __builtin_amdgcn_mfma_f32_32x32x16_bf16(al, bkv, acc[t], 0, 0, 0);
            }
        }
        // C layout (m74/m101): col=l5, row=(r&3)+8*(r>>2)+4*hi5
        // -> reg-quad a holds 4 consecutive rows (rowgroup 2a+hi5)
#pragma unroll
        for (int t = 0; t < 4; ++t) {
#pragma unroll
            for (int a = 0; a < 4; ++a) {
                union { uint2 v; unsigned short u[4]; } pk;
#pragma unroll
                for (int bb = 0; bb < 4; ++bb) pk.u[bb] = f2h(acc[t][4 * a + bb]);
                S4[2 * a + hi5][key0 + t * 32 + l5] = pk.v;
            }
        }
    }
    __syncthreads();

    // ---------------- phase 2: entmax, 2 rows per wave ----------------
    const int g  = wv >> 1;                 // rowgroup 0..7
    const int sp = wv & 1;                  // sub-pair: rows 4g+2sp+{0,1}

    // lane's dword for key c*64+lane holds BOTH sub-rows (halfwords)
    const unsigned int* Sw = reinterpret_cast<const unsigned int*>(&S4[g][0]);
    unsigned int raw[32];
#pragma unroll
    for (int c = 0; c < 32; ++c) raw[c] = Sw[2 * (c * 64 + lane) + sp];

    const half2v hzero = {(_Float16)0.0f, (_Float16)0.0f};

#pragma unroll
    for (int s = 0; s < 2; ++s) {
        // build f16x2 key-pairs for this sub-row: halfword s of each dword
        half2v z[16];
#pragma unroll
        for (int i = 0; i < 16; ++i) {
            const unsigned int merged = __builtin_amdgcn_perm(
                raw[2 * i + 1], raw[2 * i],
                s ? 0x07060302u : 0x05040100u);
            union { unsigned int u; half2v h; } cv;
            cv.u = merged;
            z[i] = cv.h;
        }

        // row max (f32)
        float m = -1e30f;
#pragma unroll
        for (int i = 0; i < 16; ++i)
            m = fmaxf(m, fmaxf((float)z[i].x, (float)z[i].y));
#pragma unroll
        for (int off = 32; off >= 1; off >>= 1)
            m = fmaxf(m, __shfl_xor(m, off, 64));

        // bisection: sum max(s - th, 0)^2 = 512, th in [m - 1/c, m]
        float lo = m - THETA_SPAN, hi = m;
        float th = 0.0f;
        for (int it = 0; it < 11; ++it) {
            th = 0.5f * (lo + hi);
            const _Float16 thh = (_Float16)th;
            const half2v nth2 = {(_Float16)-thh, (_Float16)-thh};
            float f = 0.0f;
#pragma unroll
            for (int i = 0; i < 16; ++i) {
                half2v d = z[i] + nth2;                       // v_pk_add_f16
                d = __builtin_elementwise_max(d, hzero);      // v_pk_max_f16
                f = fdot2acc(d, d, f);                        // v_dot2_f32_f16
            }
#pragma unroll
            for (int off = 32; off >= 1; off >>= 1)
                f += __shfl_xor(f, off, 64);
            if (f >= 512.0f) lo = th; else hi = th;
        }
        th = 0.5f * (lo + hi);
        th = (float)((_Float16)th);   // evaluate at the quantized theta

        // epilogue: p = max(s-th,0)^2 / 512, f32 coalesced stores
        float* orow = out + (size_t)(row0 + 4 * g + 2 * sp + s) * SEQ + lane;
#pragma unroll
        for (int i = 0; i < 16; ++i) {
            const float d0 = fmaxf((float)z[i].x - th, 0.0f);
            const float d1 = fmaxf((float)z[i].y - th, 0.0f);
            orow[(size_t)(2 * i) * 64]     = d0 * d0 * (1.0f / 512.0f);
            orow[(size_t)(2 * i + 1) * 64] = d1 * d1 * (1.0f / 512.0f);
        }
    }
}

// ---------------------------------------------------------------------------
extern "C" void kernel_launch(void* const* d_in, const int* in_sizes, int n_in,
                              void* d_out, int out_size, void* d_ws, size_t ws_size,
                              hipStream_t stream) {
    const float* x_c = (const float*)d_in[0];
    const float* x_n = (const float*)d_in[1];
    const float* Wq  = (const float*)d_in[2];
    const float* bq  = (const float*)d_in[3];
    const float* Wk  = (const float*)d_in[4];
    const float* bk  = (const float*)d_in[5];
    float* out = (float*)d_out;

    char* ws = (char*)d_ws;
    unsigned short* Qhi = (unsigned short*)ws;                        // 4 MB
    unsigned short* Qlo = (unsigned short*)(ws + ((size_t)4 << 20));  // 4 MB
    unsigned short* Kbl = (unsigned short*)(ws + ((size_t)8 << 20));  // 4 MB

    proj_qk<<<dim3(NROWS / 64, 2), 256, 0, stream>>>(
        x_c, x_n, Wq, bq, Wk, bk, Qhi, Qlo, Kbl);
    attn_fused<<<NROWS / 32, 1024, 0, stream>>>(
        (const __bf16*)Qhi, (const __bf16*)Qlo, (const __bf16*)Kbl, out);
}